// Round 3
// baseline (869.301 us; speedup 1.0000x reference)
//
#include <hip/hip_runtime.h>
#include <cstdint>
#include <cstddef>

#define S_DIM 4096
#define B_DIM 32
#define H_DIM 512
#define M_DIM (S_DIM * B_DIM)

typedef unsigned short u16;
typedef unsigned int u32;
typedef float f32x4 __attribute__((ext_vector_type(4)));
typedef float f32x8 __attribute__((ext_vector_type(8)));
typedef __bf16 bf16x8 __attribute__((ext_vector_type(8)));

__device__ __forceinline__ u16 f2bf(float v) {
    union { float f; u32 u; } a; a.f = v;
    u32 r = a.u + 0x7fffu + ((a.u >> 16) & 1u);   // RNE
    return (u16)(r >> 16);
}
__device__ __forceinline__ float bf2f(u16 b) {
    union { float f; u32 u; } a; a.u = ((u32)b) << 16; return a.f;
}
__device__ __forceinline__ void split_bf(float v, u16& h, u16& l) {
    h = f2bf(v);
    l = f2bf(v - bf2f(h));
}

// ---------------------------------------------------------------------------
// Kernel 1: split W (fp32 [H,H] row-major j,k) into bf16 hi/lo pair (RNE).
// ---------------------------------------------------------------------------
__global__ void prep_w(const float* __restrict__ W,
                       u16* __restrict__ Wh, u16* __restrict__ Wl) {
    int i = blockIdx.x * 256 + threadIdx.x;       // grid 1024 -> 262144 elems
    float w = W[i];
    u16 h, l;
    split_bf(w, h, l);
    Wh[i] = h; Wl[i] = l;
}

// ---------------------------------------------------------------------------
// In-register RTZ bf16 split helpers.
// pack_hi8: take top 16 bits of each of 8 floats (RTZ bf16), pack to bf16x8.
//   word j = (hi16(v[2j+1])<<16) | hi16(v[2j])  via v_perm_b32.
// trunc_residual: v - as_float(hi16(v)<<16)  (exact in fp32).
// (ah + al) represents v to ~2^-16 relative; dropped al*bl MFMA term ~2^-17.
// ---------------------------------------------------------------------------
union Bf8u { bf16x8 v; u32 w[4]; };

__device__ __forceinline__ bf16x8 pack_hi8(const f32x8& v) {
    Bf8u r;
    #pragma unroll
    for (int j = 0; j < 4; ++j)
        r.w[j] = __builtin_amdgcn_perm(
            __float_as_uint(v[2 * j + 1]),   // S0: bytes 4-7
            __float_as_uint(v[2 * j]),       // S1: bytes 0-3
            0x07060302u);                    // [v0.b2, v0.b3, v1.b2, v1.b3]
    return r.v;
}
__device__ __forceinline__ f32x8 trunc_residual(const f32x8& v) {
    f32x8 lo;
    #pragma unroll
    for (int j = 0; j < 8; ++j)
        lo[j] = v[j] - __uint_as_float(__float_as_uint(v[j]) & 0xffff0000u);
    return lo;
}

// ---------------------------------------------------------------------------
// Kernel 2 (v3): ZERO-BARRIER direct GEMM. 128x128 tile, 4 waves (2x2),
// no LDS in the K-loop:
//   A: per-lane 32B enc loads (row ar, cols g*8..+8) * hid (L1), RTZ hi/lo
//      split in registers -> MFMA A-fragments directly.
//   B: per-lane 16B Wh/Wl fragment loads (L2-resident, 1MB total).
//   C[m,j] = sum_k (enc*hid)[m,k] * W[j,k]  via 3-pass bf16 MFMA, fp32 acc.
// enc prefetched one K-step ahead (ping-pong register sets). Only barrier:
// epilogue rowsum reduction.
// ---------------------------------------------------------------------------
__global__ __launch_bounds__(256, 2) void bigram_gemm_direct2(
    const float* __restrict__ enc,
    const float* __restrict__ hid,
    const u16* __restrict__ Wh, const u16* __restrict__ Wl,
    float* __restrict__ Lp)
{
    __shared__ float rowsum[2][128];

    const int tid  = threadIdx.x;
    const int wave = tid >> 6;
    const int lane = tid & 63;
    const int wr   = wave >> 1;                   // wave row (0..1)
    const int wc   = wave & 1;                    // wave col (0..1)
    // bijective XCD-chunked swizzle (nwg=4096, 8 XCDs)
    const int logical = (blockIdx.x & 7) * 512 + (blockIdx.x >> 3);
    const int jt   = logical & 3;
    const int mt   = logical >> 2;
    const int m0   = mt * 128;
    const int j0   = jt * 128;
    const int g    = lane >> 4;                   // quad 0..3
    const int cl   = lane & 15;

    // A: enc row pointers for mf=0..3 (rows m0 + wr*64 + mf*16 + cl)
    const float* pe0 = enc + (size_t)(m0 + wr * 64 +  0 + cl) * H_DIM + g * 8;
    const float* pe1 = enc + (size_t)(m0 + wr * 64 + 16 + cl) * H_DIM + g * 8;
    const float* pe2 = enc + (size_t)(m0 + wr * 64 + 32 + cl) * H_DIM + g * 8;
    const float* pe3 = enc + (size_t)(m0 + wr * 64 + 48 + cl) * H_DIM + g * 8;
    // hid rows: b = (row)&31 = cl + 16*(mf&1)
    const float* ph0 = hid + (size_t)cl * H_DIM + g * 8;
    const float* ph1 = hid + (size_t)(cl + 16) * H_DIM + g * 8;
    // B: Wh/Wl row pointers for nf=0..3 (rows j0 + wc*64 + nf*16 + cl)
    const u16* pbh0 = Wh + (size_t)(j0 + wc * 64 +  0 + cl) * H_DIM + g * 8;
    const u16* pbh1 = Wh + (size_t)(j0 + wc * 64 + 16 + cl) * H_DIM + g * 8;
    const u16* pbh2 = Wh + (size_t)(j0 + wc * 64 + 32 + cl) * H_DIM + g * 8;
    const u16* pbh3 = Wh + (size_t)(j0 + wc * 64 + 48 + cl) * H_DIM + g * 8;
    const u16* pbl0 = Wl + (size_t)(j0 + wc * 64 +  0 + cl) * H_DIM + g * 8;
    const u16* pbl1 = Wl + (size_t)(j0 + wc * 64 + 16 + cl) * H_DIM + g * 8;
    const u16* pbl2 = Wl + (size_t)(j0 + wc * 64 + 32 + cl) * H_DIM + g * 8;
    const u16* pbl3 = Wl + (size_t)(j0 + wc * 64 + 48 + cl) * H_DIM + g * 8;

    f32x4 acc[4][4];
    #pragma unroll
    for (int mf = 0; mf < 4; ++mf)
        #pragma unroll
        for (int nf = 0; nf < 4; ++nf)
            acc[mf][nf] = (f32x4){0.f, 0.f, 0.f, 0.f};

    // prologue: load enc K-window 0 into set A
    f32x8 xa0 = *(const f32x8*)(pe0);
    f32x8 xa1 = *(const f32x8*)(pe1);
    f32x8 xa2 = *(const f32x8*)(pe2);
    f32x8 xa3 = *(const f32x8*)(pe3);
    f32x8 xb0, xb1, xb2, xb3;

#define COMPUTE(E0, E1, E2, E3, KT)                                            \
  {                                                                            \
    const int ko = (KT) * 32;                                                  \
    const f32x8 h0 = *(const f32x8*)(ph0 + ko);                                \
    const f32x8 h1 = *(const f32x8*)(ph1 + ko);                                \
    bf16x8 ah[4], al[4];                                                       \
    {                                                                          \
      f32x8 v;                                                                 \
      v = E0 * h0; ah[0] = pack_hi8(v); al[0] = pack_hi8(trunc_residual(v));   \
      v = E1 * h1; ah[1] = pack_hi8(v); al[1] = pack_hi8(trunc_residual(v));   \
      v = E2 * h0; ah[2] = pack_hi8(v); al[2] = pack_hi8(trunc_residual(v));   \
      v = E3 * h1; ah[3] = pack_hi8(v); al[3] = pack_hi8(trunc_residual(v));   \
    }                                                                          \
    bf16x8 bh[4], bl[4];                                                       \
    bh[0] = *(const bf16x8*)(pbh0 + ko); bl[0] = *(const bf16x8*)(pbl0 + ko);  \
    bh[1] = *(const bf16x8*)(pbh1 + ko); bl[1] = *(const bf16x8*)(pbl1 + ko);  \
    bh[2] = *(const bf16x8*)(pbh2 + ko); bl[2] = *(const bf16x8*)(pbl2 + ko);  \
    bh[3] = *(const bf16x8*)(pbh3 + ko); bl[3] = *(const bf16x8*)(pbl3 + ko);  \
    _Pragma("unroll")                                                          \
    for (int nf = 0; nf < 4; ++nf) {                                           \
      _Pragma("unroll")                                                        \
      for (int mf = 0; mf < 4; ++mf) {                                         \
        acc[mf][nf] = __builtin_amdgcn_mfma_f32_16x16x32_bf16(ah[mf], bh[nf], acc[mf][nf], 0, 0, 0); \
        acc[mf][nf] = __builtin_amdgcn_mfma_f32_16x16x32_bf16(ah[mf], bl[nf], acc[mf][nf], 0, 0, 0); \
        acc[mf][nf] = __builtin_amdgcn_mfma_f32_16x16x32_bf16(al[mf], bh[nf], acc[mf][nf], 0, 0, 0); \
      }                                                                        \
    }                                                                          \
  }

    #pragma unroll 1
    for (int kt = 0; kt < 16; kt += 2) {
        {   // prefetch kt+1 into set B (always valid: kt+1 <= 15)
            const int ko = (kt + 1) * 32;
            xb0 = *(const f32x8*)(pe0 + ko);
            xb1 = *(const f32x8*)(pe1 + ko);
            xb2 = *(const f32x8*)(pe2 + ko);
            xb3 = *(const f32x8*)(pe3 + ko);
        }
        COMPUTE(xa0, xa1, xa2, xa3, kt);
        if (kt + 2 < 16) {   // prefetch kt+2 into set A
            const int ko = (kt + 2) * 32;
            xa0 = *(const f32x8*)(pe0 + ko);
            xa1 = *(const f32x8*)(pe1 + ko);
            xa2 = *(const f32x8*)(pe2 + ko);
            xa3 = *(const f32x8*)(pe3 + ko);
        }
        COMPUTE(xb0, xb1, xb2, xb3, kt + 1);
    }
#undef COMPUTE

    // ---- epilogue: rowsum[row] = sum_col enc[row-32, col] * C ----
    #pragma unroll
    for (int mf = 0; mf < 4; ++mf) {
        float rs0 = 0.f, rs1 = 0.f, rs2 = 0.f, rs3 = 0.f;
        const int growb = m0 + wr * 64 + mf * 16 + g * 4;
        #pragma unroll
        for (int nf = 0; nf < 4; ++nf) {
            const int gcol = j0 + wc * 64 + nf * 16 + cl;
            float ee0 = (growb + 0 >= B_DIM) ? enc[(size_t)(growb + 0 - B_DIM) * H_DIM + gcol] : 0.f;
            float ee1 = (growb + 1 >= B_DIM) ? enc[(size_t)(growb + 1 - B_DIM) * H_DIM + gcol] : 0.f;
            float ee2 = (growb + 2 >= B_DIM) ? enc[(size_t)(growb + 2 - B_DIM) * H_DIM + gcol] : 0.f;
            float ee3 = (growb + 3 >= B_DIM) ? enc[(size_t)(growb + 3 - B_DIM) * H_DIM + gcol] : 0.f;
            rs0 += acc[mf][nf][0] * ee0;
            rs1 += acc[mf][nf][1] * ee1;
            rs2 += acc[mf][nf][2] * ee2;
            rs3 += acc[mf][nf][3] * ee3;
        }
        #pragma unroll
        for (int off = 1; off < 16; off <<= 1) {
            rs0 += __shfl_xor(rs0, off);
            rs1 += __shfl_xor(rs1, off);
            rs2 += __shfl_xor(rs2, off);
            rs3 += __shfl_xor(rs3, off);
        }
        if (cl == 0) {
            const int rb = wr * 64 + mf * 16 + g * 4;   // disjoint across waves
            rowsum[wc][rb + 0] = rs0;
            rowsum[wc][rb + 1] = rs1;
            rowsum[wc][rb + 2] = rs2;
            rowsum[wc][rb + 3] = rs3;
        }
    }
    __syncthreads();
    if (tid < 128) {
        const int gm = m0 + tid;
        if (gm >= B_DIM) {
            Lp[(size_t)jt * M_DIM + (size_t)(gm & 31) * S_DIM + (gm >> 5)] =
                rowsum[0][tid] + rowsum[1][tid];
        }
    }
}

// ---------------------------------------------------------------------------
// Kernel 3a: per-b dots: Aux[b] = { h.aff0, h.aff1, h.aff2, h.enc[0,b] }
// ---------------------------------------------------------------------------
__global__ __launch_bounds__(256) void prep_aff(
    const float* __restrict__ enc,
    const float* __restrict__ hid,
    const float* __restrict__ aff,
    float* __restrict__ Aux)
{
    __shared__ float w[4][4];
    const int b    = blockIdx.x;
    const int tid  = threadIdx.x;
    const int wave = tid >> 6;
    const int lane = tid & 63;

    float p0 = 0.f, p1 = 0.f, p2 = 0.f, p3 = 0.f;
    #pragma unroll
    for (int it = 0; it < 2; ++it) {
        const int h = tid + it * 256;
        const float hv = hid[b * H_DIM + h];
        p0 += hv * aff[h * 3 + 0];
        p1 += hv * aff[h * 3 + 1];
        p2 += hv * aff[h * 3 + 2];
        p3 += hv * enc[(size_t)b * H_DIM + h];
    }
    #pragma unroll
    for (int off = 32; off > 0; off >>= 1) {
        p0 += __shfl_xor(p0, off);
        p1 += __shfl_xor(p1, off);
        p2 += __shfl_xor(p2, off);
        p3 += __shfl_xor(p3, off);
    }
    if (lane == 0) { w[wave][0] = p0; w[wave][1] = p1; w[wave][2] = p2; w[wave][3] = p3; }
    __syncthreads();
    if (tid < 4)
        Aux[b * 4 + tid] = w[0][tid] + w[1][tid] + w[2][tid] + w[3][tid];
}

// ---------------------------------------------------------------------------
// Kernel 3b: per-(b,strip) logits + partial (max, sum-of-exp).
// grid = 32*8 blocks of 256, each covers 512 s.
// ---------------------------------------------------------------------------
__global__ __launch_bounds__(256) void sm_partial(
    const float* __restrict__ emb,
    const float* __restrict__ Lp,
    const float* __restrict__ Aux,
    float* __restrict__ Lg,
    float* __restrict__ Part)
{
    __shared__ float wm[4];
    __shared__ float wsum[4];
    const int b     = blockIdx.x >> 3;
    const int strip = blockIdx.x & 7;
    const int tid   = threadIdx.x;
    const int wave  = tid >> 6;
    const int lane  = tid & 63;

    const float ha0 = Aux[b * 4 + 0], ha1 = Aux[b * 4 + 1],
                ha2 = Aux[b * 4 + 2], s0dot = Aux[b * 4 + 3];

    float lgv[2];
    float mx = -3.4e38f;
    #pragma unroll
    for (int it = 0; it < 2; ++it) {
        const int s = strip * 512 + it * 256 + tid;
        const size_t base = (size_t)b * S_DIM + s;
        const float ed = (s == 0) ? s0dot
            : (Lp[base] + Lp[(size_t)M_DIM + base] + Lp[2 * (size_t)M_DIM + base] + Lp[3 * (size_t)M_DIM + base]);
        const float* e = emb + (size_t)(s * B_DIM + b) * 3;
        const float lg = ed + ha0 * e[0] + ha1 * e[1] + ha2 * e[2];
        Lg[(size_t)b * S_DIM + s] = lg;
        lgv[it] = lg;
        mx = fmaxf(mx, lg);
    }
    #pragma unroll
    for (int off = 32; off > 0; off >>= 1) mx = fmaxf(mx, __shfl_xor(mx, off));
    if (lane == 0) wm[wave] = mx;
    __syncthreads();
    mx = fmaxf(fmaxf(wm[0], wm[1]), fmaxf(wm[2], wm[3]));

    float sum = __expf(lgv[0] - mx) + __expf(lgv[1] - mx);
    #pragma unroll
    for (int off = 32; off > 0; off >>= 1) sum += __shfl_xor(sum, off);
    if (lane == 0) wsum[wave] = sum;
    __syncthreads();
    if (tid == 0) {
        Part[(size_t)(b * 8 + strip) * 2 + 0] = mx;
        Part[(size_t)(b * 8 + strip) * 2 + 1] = wsum[0] + wsum[1] + wsum[2] + wsum[3];
    }
}

// ---------------------------------------------------------------------------
// Kernel 3c: combine partials, write normalized softmax.
// ---------------------------------------------------------------------------
__global__ __launch_bounds__(256) void sm_final(
    const float* __restrict__ Lg,
    const float* __restrict__ Part,
    float* __restrict__ out)
{
    const int b     = blockIdx.x >> 3;
    const int strip = blockIdx.x & 7;
    const int tid   = threadIdx.x;

    float M = -3.4e38f;
    #pragma unroll
    for (int i = 0; i < 8; ++i) M = fmaxf(M, Part[(size_t)(b * 8 + i) * 2]);
    float S = 0.f;
    #pragma unroll
    for (int i = 0; i < 8; ++i)
        S += Part[(size_t)(b * 8 + i) * 2 + 1] * __expf(Part[(size_t)(b * 8 + i) * 2] - M);
    const float inv = 1.0f / S;

    #pragma unroll
    for (int it = 0; it < 2; ++it) {
        const int s = strip * 512 + it * 256 + tid;
        out[(size_t)b * S_DIM + s] = __expf(Lg[(size_t)b * S_DIM + s] - M) * inv;
    }
}

// ---------------------------------------------------------------------------
extern "C" void kernel_launch(void* const* d_in, const int* in_sizes, int n_in,
                              void* d_out, int out_size, void* d_ws, size_t ws_size,
                              hipStream_t stream) {
    const float* hid = (const float*)d_in[0];   // [1,B,H]
    const float* enc = (const float*)d_in[1];   // [S,B,H]
    const float* emb = (const float*)d_in[2];   // [S,B,3]
    const float* Wm  = (const float*)d_in[3];   // [H,H]
    const float* aff = (const float*)d_in[4];   // [H,3]
    float* out = (float*)d_out;                 // [B,1,S]

    char* ws = (char*)d_ws;
    u16*   Wh  = (u16*)ws;                                       // 512 KB
    u16*   Wl  = (u16*)(ws + (512u << 10));                      // 512 KB
    float* Lp  = (float*)(ws + (1024u << 10));                   // 2 MB: Lp[4][B][S]
    float* Aux = (float*)(ws + (3072u << 10));                   // 512 B
    float* Lg  = (float*)(ws + (3072u << 10) + 1024);            // 512 KB
    float* Part= (float*)(ws + (3072u << 10) + 1024 + (512u << 10)); // 2 KB

    hipLaunchKernelGGL(prep_w, dim3(1024), dim3(256), 0, stream, Wm, Wh, Wl);
    hipLaunchKernelGGL(prep_aff, dim3(32), dim3(256), 0, stream, enc, hid, aff, Aux);
    hipLaunchKernelGGL(bigram_gemm_direct2, dim3(4096), dim3(256), 0, stream,
                       enc, hid, Wh, Wl, Lp);
    hipLaunchKernelGGL(sm_partial, dim3(256), dim3(256), 0, stream,
                       emb, Lp, Aux, Lg, Part);
    hipLaunchKernelGGL(sm_final, dim3(256), dim3(256), 0, stream,
                       Lg, Part, out);
}

// Round 5
// 560.333 us; speedup vs baseline: 1.5514x; 1.5514x over previous
//
#include <hip/hip_runtime.h>
#include <cstdint>
#include <cstddef>

#define S_DIM 4096
#define B_DIM 32
#define H_DIM 512
#define M_DIM (S_DIM * B_DIM)

typedef unsigned short u16;
typedef unsigned int u32;
typedef float f32x4 __attribute__((ext_vector_type(4)));
typedef __bf16 bf16x8 __attribute__((ext_vector_type(8)));

__device__ __forceinline__ u16 f2bf(float v) {
    union { float f; u32 u; } a; a.f = v;
    u32 r = a.u + 0x7fffu + ((a.u >> 16) & 1u);   // RNE
    return (u16)(r >> 16);
}
__device__ __forceinline__ float bf2f(u16 b) {
    union { float f; u32 u; } a; a.u = ((u32)b) << 16; return a.f;
}
__device__ __forceinline__ void split_bf(float v, u16& h, u16& l) {
    h = f2bf(v);
    l = f2bf(v - bf2f(h));
}

// async global->LDS, 16B per lane, dest = wave-uniform base + lane*16
__device__ __forceinline__ void gl2lds16(const void* g, void* l) {
    __builtin_amdgcn_global_load_lds(
        (const __attribute__((address_space(1))) unsigned int*)g,
        (__attribute__((address_space(3))) unsigned int*)l,
        16, 0, 0);
}

// ---------------------------------------------------------------------------
// Kernel 1: build Wsplit (fragment-major, TRANSPOSED W) from fp32 W [j,k].
// Fragment layout (u16 units):
//   off = kt*32768 + tt*1024 + hl*512 + lane*8 + e
//   value = bf16 hi/lo of W[j = kt*32 + g*8 + e][k = tt*16 + cl],
//   lane = g*16+cl.  (B-operand of C = enc @ W: B[n=k][kappa=j].)
// A GEMM block (n-tile nt) reads tt in [nt*8, nt*8+8) -> contiguous 16KB per
// K-step -> linear gl2lds staging AND conflict-free contiguous frag reads.
// ---------------------------------------------------------------------------
__global__ __launch_bounds__(256) void prep_w_swz(
    const float* __restrict__ W, u16* __restrict__ Wsp)
{
    const int t    = blockIdx.x * 256 + threadIdx.x;   // 0..32767
    const int kt   = t >> 11;
    const int rem  = t & 2047;
    const int tt   = rem >> 6;
    const int lane = rem & 63;
    const int g    = lane >> 4;
    const int cl   = lane & 15;
    const int jb   = kt * 32 + g * 8;
    const int k    = tt * 16 + cl;
    u16* po = Wsp + (size_t)kt * 32768 + tt * 1024 + lane * 8;
    #pragma unroll
    for (int e = 0; e < 8; ++e) {
        u16 hi, lo;
        split_bf(W[(size_t)(jb + e) * H_DIM + k], hi, lo);
        po[e] = hi;
        po[512 + e] = lo;
    }
}

// ---------------------------------------------------------------------------
// In-register RTZ bf16 split of 8 fp32 (two f32x4) -> hi/lo bf16x8.
// ---------------------------------------------------------------------------
union Bf8u { bf16x8 v; u32 w[4]; };

__device__ __forceinline__ void split8(f32x4 v0, f32x4 v1, bf16x8& h8, bf16x8& l8) {
    float v[8] = {v0.x, v0.y, v0.z, v0.w, v1.x, v1.y, v1.z, v1.w};
    Bf8u H, L;
    #pragma unroll
    for (int j = 0; j < 4; ++j) {
        const u32 u0 = __float_as_uint(v[2 * j]);
        const u32 u1 = __float_as_uint(v[2 * j + 1]);
        H.w[j] = __builtin_amdgcn_perm(u1, u0, 0x07060302u);
        const float r0 = v[2 * j]     - __uint_as_float(u0 & 0xffff0000u);
        const float r1 = v[2 * j + 1] - __uint_as_float(u1 & 0xffff0000u);
        L.w[j] = __builtin_amdgcn_perm(__float_as_uint(r1), __float_as_uint(r0),
                                       0x07060302u);
    }
    h8 = H.v; l8 = L.v;
}

// ---------------------------------------------------------------------------
// Kernel 2 (v4b): C[m',k] = sum_j enc[m',j] * W[j,k]  (h factored out!)
//   epilogue: Lp[m'+32] = sum_k C[m',k] * enc[m'+32,k] * hid[m'&31,k]
// 128x128 tile, 4 waves. A: raw fp32 enc staged via gl2lds with 16B-granular
// XOR source swizzle (c16 ^= row&7 -> bank-optimal ds_read_b128), single-
// buffered, split to bf16 hi/lo at consume. B: staged from fragment-major
// Wsp (linear copy, contiguous frag reads, zero conflicts), double-buffered.
// 49KB LDS -> 3 blocks/CU. Two barriers per K-step; all global issue sits
// between them, under split+MFMA cover.
// ---------------------------------------------------------------------------
__global__ __launch_bounds__(256, 3) void bigram_gemm_v4(
    const float* __restrict__ enc,
    const float* __restrict__ hid,
    const u16* __restrict__ Wsp,
    float* __restrict__ Lp)
{
    __shared__ float sA[128 * 32];      // 16 KB, row stride 128B, c16-swizzled
    __shared__ u16   sB[2][8192];       // 32 KB, fragment-major (dbuf)
    __shared__ float rowsum[2][128];    // 1 KB

    const int tid  = threadIdx.x;
    const int wave = tid >> 6;
    const int lane = tid & 63;
    const int wr   = wave >> 1;
    const int wc   = wave & 1;
    // bijective XCD-chunked swizzle (nwg=4096, 8 XCDs)
    const int logical = (blockIdx.x & 7) * 512 + (blockIdx.x >> 3);
    const int nt   = logical & 3;
    const int mt   = logical >> 2;
    const int m0   = mt * 128;
    const int g    = lane >> 4;
    const int cl   = lane & 15;

    // ---- A staging source (per-lane, pre-swizzled at 16B granularity):
    //      lane covers row r = wave*32 + seg*8 + (lane>>3), LDS c16 = lane&7,
    //      sourcing enc chunk16 (lane&7) ^ (r&7); r&7 == (lane>>3)&7.
    const int arow = wave * 32 + (lane >> 3);
    const int acol = (((lane & 7) ^ ((lane >> 3) & 7)) << 2);   // floats
    const float* peA = enc + (size_t)(m0 + arow) * H_DIM + acol;

    // ---- B staging source: 16KB per K-step (8 tt-segments), wave does 4KB.
    const u16* pwB = Wsp + (size_t)nt * 8192 + wave * 2048 + lane * 8;

    // ---- A fragment read geometry: row = wr*64 + mf*16 + cl (row&7 = cl&7),
    //      enc chunk16 {2g, 2g+1} live at LDS c16 {2g^(cl&7), (2g^(cl&7))^1}.
    const int arb = (wr * 64 + cl) * 128;              // byte row base (mf=0)
    const int ac0 = ((2 * g) ^ (cl & 7)) << 4;         // byte chunk for elems 0-3
    const int ac1 = ((2 * g + 1) ^ (cl & 7)) << 4;     // byte chunk for elems 4-7
    const char* sAb = (const char*)sA;
    // ---- B fragment read base (byte): + CUR*16384 + nf*2048 (+1024 for lo).
    const int bfo = wc * 8192 + lane * 16;
    const char* sBb = (const char*)sB;

    f32x4 acc[4][4];
    #pragma unroll
    for (int mf = 0; mf < 4; ++mf)
        #pragma unroll
        for (int nf = 0; nf < 4; ++nf)
            acc[mf][nf] = (f32x4){0.f, 0.f, 0.f, 0.f};

#define STAGE_A(KT) do {                                                       \
    const float* _s = peA + (size_t)(KT) * 32;                                 \
    char* _d = (char*)sA + wave * 4096;                                        \
    gl2lds16(_s,          _d);                                                 \
    gl2lds16(_s +  4096,  _d + 1024);                                          \
    gl2lds16(_s +  8192,  _d + 2048);                                          \
    gl2lds16(_s + 12288,  _d + 3072);                                          \
  } while (0)

#define STAGE_B(KT, CUR) do {                                                  \
    const u16* _s = pwB + (size_t)(KT) * 32768;                                \
    char* _d = (char*)sB + (CUR) * 16384 + wave * 4096;                        \
    gl2lds16(_s,         _d);                                                  \
    gl2lds16(_s +  512,  _d + 1024);                                           \
    gl2lds16(_s + 1024,  _d + 2048);                                           \
    gl2lds16(_s + 1536,  _d + 3072);                                           \
  } while (0)

    // ---- prologue: stage K-step 0
    STAGE_A(0);
    STAGE_B(0, 0);
    __syncthreads();

#define GEMM_STEP(KT, CUR)                                                     \
  {                                                                            \
    f32x4 aa[4][2];                                                            \
    _Pragma("unroll")                                                          \
    for (int mf = 0; mf < 4; ++mf) {                                           \
      aa[mf][0] = *(const f32x4*)(sAb + arb + mf * 2048 + ac0);                \
      aa[mf][1] = *(const f32x4*)(sAb + arb + mf * 2048 + ac1);                \
    }                                                                          \
    bf16x8 bh[4], bl[4];                                                       \
    _Pragma("unroll")                                                          \
    for (int nf = 0; nf < 4; ++nf) {                                           \
      bh[nf] = *(const bf16x8*)(sBb + (CUR) * 16384 + bfo + nf * 2048);        \
      bl[nf] = *(const bf16x8*)(sBb + (CUR) * 16384 + bfo + nf * 2048 + 1024); \
    }                                                                          \
    __syncthreads(); /* b1: LDS frag reads drained; no vmem outstanding */     \
    if ((KT) < 15) {                                                           \
      STAGE_A((KT) + 1);                                                       \
      STAGE_B((KT) + 1, (CUR) ^ 1);                                            \
    }                                                                          \
    __builtin_amdgcn_s_setprio(1);                                             \
    _Pragma("unroll")                                                          \
    for (int mf = 0; mf < 4; ++mf) {                                           \
      bf16x8 ah, al;                                                           \
      split8(aa[mf][0], aa[mf][1], ah, al);                                    \
      _Pragma("unroll")                                                        \
      for (int nf = 0; nf < 4; ++nf) {                                         \
        acc[mf][nf] = __builtin_amdgcn_mfma_f32_16x16x32_bf16(ah, bh[nf], acc[mf][nf], 0, 0, 0); \
        acc[mf][nf] = __builtin_amdgcn_mfma_f32_16x16x32_bf16(ah, bl[nf], acc[mf][nf], 0, 0, 0); \
        acc[mf][nf] = __builtin_amdgcn_mfma_f32_16x16x32_bf16(al, bh[nf], acc[mf][nf], 0, 0, 0); \
      }                                                                        \
    }                                                                          \
    __builtin_amdgcn_s_setprio(0);                                             \
    __syncthreads(); /* b2: gl2lds drained under split+MFMA cover */           \
  }

    for (int kt = 0; kt < 16; kt += 2) {
        GEMM_STEP(kt, 0);
        GEMM_STEP(kt + 1, 1);
    }
#undef GEMM_STEP
#undef STAGE_A
#undef STAGE_B

    // ---- epilogue: Lp[r+32] = sum_k C[r,k] * enc[r+32,k] * hid[r&31,k] ----
    #pragma unroll
    for (int mf = 0; mf < 4; ++mf) {
        float rs0 = 0.f, rs1 = 0.f, rs2 = 0.f, rs3 = 0.f;
        const int r4 = m0 + wr * 64 + mf * 16 + g * 4;
        #pragma unroll
        for (int nf = 0; nf < 4; ++nf) {
            const int gcol = nt * 128 + wc * 64 + nf * 16 + cl;
            float e0 = (r4 + 0 < M_DIM - 32)
                ? enc[(size_t)(r4 + 32) * H_DIM + gcol] * hid[((r4 + 0) & 31) * H_DIM + gcol] : 0.f;
            float e1 = (r4 + 1 < M_DIM - 32)
                ? enc[(size_t)(r4 + 33) * H_DIM + gcol] * hid[((r4 + 1) & 31) * H_DIM + gcol] : 0.f;
            float e2 = (r4 + 2 < M_DIM - 32)
                ? enc[(size_t)(r4 + 34) * H_DIM + gcol] * hid[((r4 + 2) & 31) * H_DIM + gcol] : 0.f;
            float e3 = (r4 + 3 < M_DIM - 32)
                ? enc[(size_t)(r4 + 35) * H_DIM + gcol] * hid[((r4 + 3) & 31) * H_DIM + gcol] : 0.f;
            rs0 += acc[mf][nf][0] * e0;
            rs1 += acc[mf][nf][1] * e1;
            rs2 += acc[mf][nf][2] * e2;
            rs3 += acc[mf][nf][3] * e3;
        }
        #pragma unroll
        for (int off = 1; off < 16; off <<= 1) {
            rs0 += __shfl_xor(rs0, off);
            rs1 += __shfl_xor(rs1, off);
            rs2 += __shfl_xor(rs2, off);
            rs3 += __shfl_xor(rs3, off);
        }
        if (cl == 0) {
            const int rb = wr * 64 + mf * 16 + g * 4;   // disjoint across waves
            rowsum[wc][rb + 0] = rs0;
            rowsum[wc][rb + 1] = rs1;
            rowsum[wc][rb + 2] = rs2;
            rowsum[wc][rb + 3] = rs3;
        }
    }
    __syncthreads();
    if (tid < 128) {
        const int gm = m0 + tid + 32;                    // output row (s>=1)
        if (gm < M_DIM) {
            Lp[(size_t)nt * M_DIM + (size_t)(gm & 31) * S_DIM + (gm >> 5)] =
                rowsum[0][tid] + rowsum[1][tid];
        }
    }
}

// ---------------------------------------------------------------------------
// Kernel 3a: per-b dots: Aux[b] = { h.aff0, h.aff1, h.aff2, h.enc[0,b] }
// ---------------------------------------------------------------------------
__global__ __launch_bounds__(256) void prep_aff(
    const float* __restrict__ enc,
    const float* __restrict__ hid,
    const float* __restrict__ aff,
    float* __restrict__ Aux)
{
    __shared__ float w[4][4];
    const int b    = blockIdx.x;
    const int tid  = threadIdx.x;
    const int wave = tid >> 6;
    const int lane = tid & 63;

    float p0 = 0.f, p1 = 0.f, p2 = 0.f, p3 = 0.f;
    #pragma unroll
    for (int it = 0; it < 2; ++it) {
        const int h = tid + it * 256;
        const float hv = hid[b * H_DIM + h];
        p0 += hv * aff[h * 3 + 0];
        p1 += hv * aff[h * 3 + 1];
        p2 += hv * aff[h * 3 + 2];
        p3 += hv * enc[(size_t)b * H_DIM + h];
    }
    #pragma unroll
    for (int off = 32; off > 0; off >>= 1) {
        p0 += __shfl_xor(p0, off);
        p1 += __shfl_xor(p1, off);
        p2 += __shfl_xor(p2, off);
        p3 += __shfl_xor(p3, off);
    }
    if (lane == 0) { w[wave][0] = p0; w[wave][1] = p1; w[wave][2] = p2; w[wave][3] = p3; }
    __syncthreads();
    if (tid < 4)
        Aux[b * 4 + tid] = w[0][tid] + w[1][tid] + w[2][tid] + w[3][tid];
}

// ---------------------------------------------------------------------------
// Kernel 3b: per-(b,strip) logits + partial (max, sum-of-exp).
// grid = 32*8 blocks of 256, each covers 512 s.
// ---------------------------------------------------------------------------
__global__ __launch_bounds__(256) void sm_partial(
    const float* __restrict__ emb,
    const float* __restrict__ Lp,
    const float* __restrict__ Aux,
    float* __restrict__ Lg,
    float* __restrict__ Part)
{
    __shared__ float wm[4];
    __shared__ float wsum[4];
    const int b     = blockIdx.x >> 3;
    const int strip = blockIdx.x & 7;
    const int tid   = threadIdx.x;
    const int wave  = tid >> 6;
    const int lane  = tid & 63;

    const float ha0 = Aux[b * 4 + 0], ha1 = Aux[b * 4 + 1],
                ha2 = Aux[b * 4 + 2], s0dot = Aux[b * 4 + 3];

    float lgv[2];
    float mx = -3.4e38f;
    #pragma unroll
    for (int it = 0; it < 2; ++it) {
        const int s = strip * 512 + it * 256 + tid;
        const size_t base = (size_t)b * S_DIM + s;
        const float ed = (s == 0) ? s0dot
            : (Lp[base] + Lp[(size_t)M_DIM + base] + Lp[2 * (size_t)M_DIM + base] + Lp[3 * (size_t)M_DIM + base]);
        const float* e = emb + (size_t)(s * B_DIM + b) * 3;
        const float lg = ed + ha0 * e[0] + ha1 * e[1] + ha2 * e[2];
        Lg[(size_t)b * S_DIM + s] = lg;
        lgv[it] = lg;
        mx = fmaxf(mx, lg);
    }
    #pragma unroll
    for (int off = 32; off > 0; off >>= 1) mx = fmaxf(mx, __shfl_xor(mx, off));
    if (lane == 0) wm[wave] = mx;
    __syncthreads();
    mx = fmaxf(fmaxf(wm[0], wm[1]), fmaxf(wm[2], wm[3]));

    float sum = __expf(lgv[0] - mx) + __expf(lgv[1] - mx);
    #pragma unroll
    for (int off = 32; off > 0; off >>= 1) sum += __shfl_xor(sum, off);
    if (lane == 0) wsum[wave] = sum;
    __syncthreads();
    if (tid == 0) {
        Part[(size_t)(b * 8 + strip) * 2 + 0] = mx;
        Part[(size_t)(b * 8 + strip) * 2 + 1] = wsum[0] + wsum[1] + wsum[2] + wsum[3];
    }
}

// ---------------------------------------------------------------------------
// Kernel 3c: combine partials, write normalized softmax.
// ---------------------------------------------------------------------------
__global__ __launch_bounds__(256) void sm_final(
    const float* __restrict__ Lg,
    const float* __restrict__ Part,
    float* __restrict__ out)
{
    const int b     = blockIdx.x >> 3;
    const int strip = blockIdx.x & 7;
    const int tid   = threadIdx.x;

    float M = -3.4e38f;
    #pragma unroll
    for (int i = 0; i < 8; ++i) M = fmaxf(M, Part[(size_t)(b * 8 + i) * 2]);
    float S = 0.f;
    #pragma unroll
    for (int i = 0; i < 8; ++i)
        S += Part[(size_t)(b * 8 + i) * 2 + 1] * __expf(Part[(size_t)(b * 8 + i) * 2] - M);
    const float inv = 1.0f / S;

    #pragma unroll
    for (int it = 0; it < 2; ++it) {
        const int s = strip * 512 + it * 256 + tid;
        out[(size_t)b * S_DIM + s] = __expf(Lg[(size_t)b * S_DIM + s] - M) * inv;
    }
}

// ---------------------------------------------------------------------------
extern "C" void kernel_launch(void* const* d_in, const int* in_sizes, int n_in,
                              void* d_out, int out_size, void* d_ws, size_t ws_size,
                              hipStream_t stream) {
    const float* hid = (const float*)d_in[0];   // [1,B,H]
    const float* enc = (const float*)d_in[1];   // [S,B,H]
    const float* emb = (const float*)d_in[2];   // [S,B,3]
    const float* Wm  = (const float*)d_in[3];   // [H,H]
    const float* aff = (const float*)d_in[4];   // [H,3]
    float* out = (float*)d_out;                 // [B,1,S]

    char* ws = (char*)d_ws;
    u16*   Wsp = (u16*)ws;                                       // 1 MB (frag-major W)
    float* Lp  = (float*)(ws + (2048u << 10));                   // 2 MB: Lp[4][B][S]
    float* Aux = (float*)(ws + (4096u << 10));                   // 512 B
    float* Part= (float*)(ws + (4096u << 10) + 1024);            // 2 KB
    float* Lg  = (float*)ws;                                     // aliases Wsp (dead by then)

    hipLaunchKernelGGL(prep_w_swz, dim3(128), dim3(256), 0, stream, Wm, Wsp);
    hipLaunchKernelGGL(prep_aff, dim3(32), dim3(256), 0, stream, enc, hid, aff, Aux);
    hipLaunchKernelGGL(bigram_gemm_v4, dim3(4096), dim3(256), 0, stream,
                       enc, hid, Wsp, Lp);
    hipLaunchKernelGGL(sm_partial, dim3(256), dim3(256), 0, stream,
                       emb, Lp, Aux, Lg, Part);
    hipLaunchKernelGGL(sm_final, dim3(256), dim3(256), 0, stream,
                       Lg, Part, out);
}